// Round 12
// baseline (141.252 us; speedup 1.0000x reference)
//
#include <hip/hip_runtime.h>
#include <hip/hip_bf16.h>

#define B_ 2
#define N_ 2048
#define C_ 256
#define H_ 8
#define HD_ 32

typedef __bf16 bhalf;
typedef bhalf bhalf8 __attribute__((ext_vector_type(8)));
typedef bhalf bhalf4 __attribute__((ext_vector_type(4)));
typedef float floatx4 __attribute__((ext_vector_type(4)));
typedef short short4v __attribute__((ext_vector_type(4)));

__device__ __forceinline__ floatx4 mfma16x16x16bf16(bhalf4 a, bhalf4 b, floatx4 c) {
#if __has_builtin(__builtin_amdgcn_mfma_f32_16x16x16_bf16)
    return __builtin_amdgcn_mfma_f32_16x16x16_bf16(a, b, c, 0, 0, 0);
#else
    return __builtin_amdgcn_mfma_f32_16x16x16bf16_1k(
        __builtin_bit_cast(short4v, a), __builtin_bit_cast(short4v, b), c, 0, 0, 0);
#endif
}

// ---------------------------------------------------------------------------
// prep_all: fused preprocessing.
//   blocks 0..63   : transpose+convert W (fp32 [k][n]) -> Wt (bf16 [n][k])
//   blocks 64..79  : point-extension vectors (dist bias rides the MFMA)
//   blocks 80..1103: feat fp32 -> bf16
// ---------------------------------------------------------------------------
__global__ __launch_bounds__(256) void prep_all(
    const float* __restrict__ Wq, const float* __restrict__ Wk,
    const float* __restrict__ Wv, const float* __restrict__ Wo,
    const float* __restrict__ pts, const float* __restrict__ feat,
    bhalf* __restrict__ Wtb, bhalf* __restrict__ qext,
    bhalf* __restrict__ kext, bhalf* __restrict__ fb)
{
    __shared__ float T[64][65];
    const int bx = blockIdx.x;
    const int t = threadIdx.x;
    if (bx < 64) {
        const int wsel = bx >> 4;
        const float* W = wsel == 0 ? Wq : (wsel == 1 ? Wk : (wsel == 2 ? Wv : Wo));
        bhalf* dst = Wtb + (size_t)wsel * (C_ * C_);
        const int tile = bx & 15;
        const int kt = (tile >> 2) * 64, nt = (tile & 3) * 64;
        const int c4 = (t & 15) * 4;
#pragma unroll
        for (int i = 0; i < 4; ++i) {
            const int r = (t >> 4) + i * 16;
            const float4 w = *(const float4*)&W[(kt + r) * C_ + nt + c4];
            T[r][c4 + 0] = w.x; T[r][c4 + 1] = w.y; T[r][c4 + 2] = w.z; T[r][c4 + 3] = w.w;
        }
        __syncthreads();
#pragma unroll
        for (int i = 0; i < 4; ++i) {
            const int n = (t >> 4) + i * 16;
            bhalf4 o;
            o[0] = (bhalf)T[c4 + 0][n]; o[1] = (bhalf)T[c4 + 1][n];
            o[2] = (bhalf)T[c4 + 2][n]; o[3] = (bhalf)T[c4 + 3][n];
            *(bhalf4*)&dst[(nt + n) * C_ + kt + c4] = o;
        }
    } else if (bx < 80) {
        const int i = (bx - 64) * 256 + t;  // < B*N
        const float x = pts[i * 3 + 0], y = pts[i * 3 + 1], z = pts[i * 3 + 2];
        const float nn = x * x + y * y + z * z;
        const bhalf hi = (bhalf)nn;
        const bhalf lo = (bhalf)(nn - (float)hi);
        bhalf8 qe, ke;
        qe[0] = (bhalf)(2.f * x); qe[1] = (bhalf)(2.f * y); qe[2] = (bhalf)(2.f * z);
        qe[3] = (bhalf)(-(float)hi); qe[4] = (bhalf)(-(float)lo);
        qe[5] = (bhalf)1.f; qe[6] = (bhalf)1.f; qe[7] = (bhalf)0.f;
        ke[0] = (bhalf)x; ke[1] = (bhalf)y; ke[2] = (bhalf)z;
        ke[3] = (bhalf)1.f; ke[4] = (bhalf)1.f;
        ke[5] = (bhalf)(-(float)hi); ke[6] = (bhalf)(-(float)lo); ke[7] = (bhalf)0.f;
        *(bhalf8*)&qext[(size_t)i * 8] = qe;
        *(bhalf8*)&kext[(size_t)i * 8] = ke;
    } else {
        const int idx = ((bx - 80) * 256 + t) * 4;  // < B*N*C
        const float4 f = *(const float4*)&feat[idx];
        bhalf4 o;
        o[0] = (bhalf)f.x; o[1] = (bhalf)f.y; o[2] = (bhalf)f.z; o[3] = (bhalf)f.w;
        *(bhalf4*)&fb[idx] = o;
    }
}

// ---------------------------------------------------------------------------
// qkv_gemm: bf16 MFMA GEMM, M-tile 32, double-buffered LDS (1 barrier/chunk).
// grid (M/32, 12): y/4 -> Wq/Wk/Wv, y%4 -> 64-col tile.
// ---------------------------------------------------------------------------
__global__ __launch_bounds__(256) void qkv_gemm(
    const bhalf* __restrict__ fb, const bhalf* __restrict__ Wtb,
    const float* __restrict__ bq, const float* __restrict__ bk,
    const float* __restrict__ bv,
    bhalf* __restrict__ qs, bhalf* __restrict__ kg, bhalf* __restrict__ vt)
{
    __shared__ __align__(16) bhalf Alds[2][32][72];
    __shared__ __align__(16) bhalf Blds[2][64][72];

    const int tid = threadIdx.x;
    const int wave = tid >> 6, lane = tid & 63;
    const int quad = lane >> 4, l16 = lane & 15;
    const int m0 = blockIdx.x * 32;
    const int which = blockIdx.y >> 2;
    const int n0 = (blockIdx.y & 3) * 64;
    const bhalf* Wt = Wtb + (size_t)which * (C_ * C_);
    const int mw = (wave & 1) * 16;
    const int cw = (wave >> 1) * 32;

    const floatx4 zacc = {0.f, 0.f, 0.f, 0.f};
    floatx4 acc[2] = {zacc, zacc};

    const int arow = tid >> 3, aoff = (tid & 7) * 8;
    const int brow = tid >> 2, boff = (tid & 3) * 16;

    bhalf8 ra  = *(const bhalf8*)&fb[(m0 + arow) * C_ + aoff];
    bhalf8 rb0 = *(const bhalf8*)&Wt[(n0 + brow) * C_ + boff];
    bhalf8 rb1 = *(const bhalf8*)&Wt[(n0 + brow) * C_ + boff + 8];
    *(bhalf8*)&Alds[0][arow][aoff] = ra;
    *(bhalf8*)&Blds[0][brow][boff] = rb0;
    *(bhalf8*)&Blds[0][brow][boff + 8] = rb1;

    int cur = 0;
    for (int kci = 0; kci < 4; ++kci) {
        __syncthreads();
        if (kci < 3) {
            const int kc = (kci + 1) * 64;
            ra  = *(const bhalf8*)&fb[(m0 + arow) * C_ + kc + aoff];
            rb0 = *(const bhalf8*)&Wt[(n0 + brow) * C_ + kc + boff];
            rb1 = *(const bhalf8*)&Wt[(n0 + brow) * C_ + kc + boff + 8];
        }
        const bhalf8 a0 = *(const bhalf8*)&Alds[cur][mw + l16][quad * 8];
        const bhalf8 a1 = *(const bhalf8*)&Alds[cur][mw + l16][32 + quad * 8];
#pragma unroll
        for (int f = 0; f < 2; ++f) {
            const bhalf8 b0 = *(const bhalf8*)&Blds[cur][cw + f * 16 + l16][quad * 8];
            const bhalf8 b1 = *(const bhalf8*)&Blds[cur][cw + f * 16 + l16][32 + quad * 8];
            acc[f] = __builtin_amdgcn_mfma_f32_16x16x32_bf16(a0, b0, acc[f], 0, 0, 0);
            acc[f] = __builtin_amdgcn_mfma_f32_16x16x32_bf16(a1, b1, acc[f], 0, 0, 0);
        }
        if (kci < 3) {
            *(bhalf8*)&Alds[cur ^ 1][arow][aoff] = ra;
            *(bhalf8*)&Blds[cur ^ 1][brow][boff] = rb0;
            *(bhalf8*)&Blds[cur ^ 1][brow][boff + 8] = rb1;
        }
        cur ^= 1;
    }

    const float scale = 0.17677669529663687f;  // 1/sqrt(32)
    const float* bias = which == 0 ? bq : (which == 1 ? bk : bv);
#pragma unroll
    for (int f = 0; f < 2; ++f) {
        const int cg = n0 + cw + f * 16 + l16;
        const float bi = bias[cg];
        const int hh = cg >> 5, dd = cg & 31;
        const int m = m0 + mw + quad * 4;     // 4 consecutive rows
        const int bb = m >> 11, nn = m & (N_ - 1);
        if (which == 2) {
            bhalf4 vw;
#pragma unroll
            for (int r = 0; r < 4; ++r) vw[r] = (bhalf)(acc[f][r] + bi);
            *(bhalf4*)&vt[(((size_t)(bb * H_ + hh) * (N_ / 64) + (nn >> 6)) * HD_ + dd) * 64 + (nn & 63)] = vw;
        } else {
#pragma unroll
            for (int r = 0; r < 4; ++r) {
                const float val = acc[f][r] + bi;
                if (which == 0)
                    qs[((size_t)(bb * H_ + hh) * N_ + nn + r) * HD_ + dd] = (bhalf)(val * scale);
                else
                    kg[((size_t)(bb * H_ + hh) * N_ + nn + r) * HD_ + dd] = (bhalf)val;
            }
        }
    }
}

// ---------------------------------------------------------------------------
// attn_kernel: LDS-FREE global-streaming attention. S^T = K @ Q^T; P^T stays
// in registers (B-layout for the K=16 PV MFMA). 32 queries/wave. K/V/kext
// fragments load directly global->register each tile (K loads coalesce to
// 1 KB/inst; all L2-resident) — no LDS, no barriers; latency hidden by TLP.
// Ext bias MFMA is K=16 (8 ext dims on quads 0-1). Fixed-max softmax, split-K.
// ---------------------------------------------------------------------------
__global__ __launch_bounds__(256) void attn_kernel(
    const bhalf* __restrict__ qs, const bhalf* __restrict__ kg,
    const bhalf* __restrict__ vt, const bhalf* __restrict__ qext,
    const bhalf* __restrict__ kext,
    bhalf* __restrict__ po, float* __restrict__ pl, int spbits)
{
    const int tid = threadIdx.x;
    const int wave = tid >> 6, lane = tid & 63;
    const int quad = lane >> 4, l16 = lane & 15;
    const int n0 = blockIdx.x * 128;
    const int h = blockIdx.y;
    const int sp = blockIdx.z & ((1 << spbits) - 1);
    const int b = blockIdx.z >> spbits;
    const int bh = b * H_ + h;

    const int qrow0 = n0 + wave * 32 + l16;
    const int qrow1 = qrow0 + 16;
    const bhalf8 bq0 = *(const bhalf8*)&qs[((size_t)bh * N_ + qrow0) * HD_ + quad * 8];
    const bhalf8 bq1 = *(const bhalf8*)&qs[((size_t)bh * N_ + qrow1) * HD_ + quad * 8];
    bhalf4 zv4;
#pragma unroll
    for (int j = 0; j < 4; ++j) zv4[j] = (bhalf)0.f;
    const bhalf4 bqe0 = (quad < 2)
        ? *(const bhalf4*)&qext[(size_t)(b * N_ + qrow0) * 8 + quad * 4] : zv4;
    const bhalf4 bqe1 = (quad < 2)
        ? *(const bhalf4*)&qext[(size_t)(b * N_ + qrow1) * 8 + quad * 4] : zv4;

    const floatx4 zacc = {0.f, 0.f, 0.f, 0.f};
    floatx4 o00 = zacc, o01 = zacc, o10 = zacc, o11 = zacc;
    float ls0 = 0.f, ls1 = 0.f;

    const int iters = (N_ >> spbits) / 64;
    const int mbase = sp * (N_ >> spbits);

    for (int it = 0; it < iters; ++it) {
        const int m0 = mbase + it * 64;
        const bhalf* kb = &kg[((size_t)bh * N_ + m0) * HD_];
        const bhalf* vb = &vt[((size_t)bh * (N_ / 64) + (m0 >> 6)) * (HD_ * 64)];
        const bhalf* eb = &kext[(size_t)(b * N_ + m0) * 8];

        // load the whole tile's fragments (clustered -> one vmcnt drain)
        bhalf8 kf[4];
        bhalf4 ef[4], vf0[4], vf1[4];
#pragma unroll
        for (int mt = 0; mt < 4; ++mt) {
            kf[mt] = *(const bhalf8*)&kb[(mt * 16 + l16) * HD_ + quad * 8];
            ef[mt] = (quad < 2)
                ? *(const bhalf4*)&eb[(mt * 16 + l16) * 8 + quad * 4] : zv4;
            vf0[mt] = *(const bhalf4*)&vb[l16 * 64 + mt * 16 + quad * 4];
            vf1[mt] = *(const bhalf4*)&vb[(16 + l16) * 64 + mt * 16 + quad * 4];
        }
#pragma unroll
        for (int mt = 0; mt < 4; ++mt) {
            floatx4 st0 = __builtin_amdgcn_mfma_f32_16x16x32_bf16(kf[mt], bq0, zacc, 0, 0, 0);
            st0 = mfma16x16x16bf16(ef[mt], bqe0, st0);
            floatx4 st1 = __builtin_amdgcn_mfma_f32_16x16x32_bf16(kf[mt], bq1, zacc, 0, 0, 0);
            st1 = mfma16x16x16bf16(ef[mt], bqe1, st1);
            bhalf4 pt0, pt1;
#pragma unroll
            for (int r = 0; r < 4; ++r) {
                const float p0 = __expf(st0[r]);
                const float p1 = __expf(st1[r]);
                ls0 += p0; ls1 += p1;
                pt0[r] = (bhalf)p0; pt1[r] = (bhalf)p1;
            }
            o00 = mfma16x16x16bf16(vf0[mt], pt0, o00);
            o01 = mfma16x16x16bf16(vf1[mt], pt0, o01);
            o10 = mfma16x16x16bf16(vf0[mt], pt1, o10);
            o11 = mfma16x16x16bf16(vf1[mt], pt1, o11);
        }
    }

    ls0 += __shfl_xor(ls0, 16); ls0 += __shfl_xor(ls0, 32);
    ls1 += __shfl_xor(ls1, 16); ls1 += __shfl_xor(ls1, 32);

    const size_t pobase = (size_t)sp * ((size_t)B_ * H_ * N_ * HD_) + (size_t)bh * N_ * HD_;
    bhalf4 w00, w01, w10, w11;
#pragma unroll
    for (int r = 0; r < 4; ++r) {
        w00[r] = (bhalf)o00[r]; w01[r] = (bhalf)o01[r];
        w10[r] = (bhalf)o10[r]; w11[r] = (bhalf)o11[r];
    }
    *(bhalf4*)&po[pobase + (size_t)qrow0 * HD_ + quad * 4] = w00;
    *(bhalf4*)&po[pobase + (size_t)qrow0 * HD_ + 16 + quad * 4] = w01;
    *(bhalf4*)&po[pobase + (size_t)qrow1 * HD_ + quad * 4] = w10;
    *(bhalf4*)&po[pobase + (size_t)qrow1 * HD_ + 16 + quad * 4] = w11;
    if (lane < 16)
        pl[(size_t)sp * (B_ * H_ * N_) + (size_t)bh * N_ + qrow0] = ls0;
    else if (lane < 32)
        pl[(size_t)sp * (B_ * H_ * N_) + (size_t)bh * N_ + qrow1] = ls1;
}

// ---------------------------------------------------------------------------
// outln_gemm: fused combine + out-proj MFMA GEMM + residual + LayerNorm.
// 512 threads = 8 waves per block; 16-row x 256-col tile, each wave owns 32
// cols. Double-buffered B-chunks.
// ---------------------------------------------------------------------------
__global__ __launch_bounds__(512) void outln_gemm(
    const bhalf* __restrict__ po, const float* __restrict__ pl,
    const bhalf* __restrict__ Wot, const float* __restrict__ bo,
    const float* __restrict__ feat, const float* __restrict__ g,
    const float* __restrict__ bb, float* __restrict__ out, int splits)
{
    __shared__ __align__(16) bhalf Alds[16][264];
    __shared__ __align__(16) bhalf Blds[2][256][40];
    __shared__ float rden[16][8];
    __shared__ float wsum[8][16][2];
    __shared__ float stats[16][2];

    const int tid = threadIdx.x;
    const int wave = tid >> 6, lane = tid & 63;
    const int quad = lane >> 4, l16 = lane & 15;
    const int row0 = blockIdx.x * 16;

    if (tid < 128) {
        const int m = tid >> 3, hh = tid & 7;
        const int grow = row0 + m;
        const int b = grow >> 11, n = grow & (N_ - 1);
        float den = 0.f;
        for (int sp = 0; sp < splits; ++sp)
            den += pl[(size_t)sp * (B_ * H_ * N_) + (size_t)(b * H_ + hh) * N_ + n];
        rden[m][hh] = 1.f / den;
    }
    __syncthreads();

    {   // A staging: 512 threads, 16 rows x 256 k; thread covers 8 k.
        const int m = tid >> 5, seg = tid & 31;
        const int hh = seg >> 2, d0 = (seg & 3) * 8;
        const int grow = row0 + m;
        const int b = grow >> 11, n = grow & (N_ - 1);
        const size_t idx = ((size_t)(b * H_ + hh) * N_ + n) * HD_ + d0;
        float num[8];
#pragma unroll
        for (int j = 0; j < 8; ++j) num[j] = 0.f;
        for (int sp = 0; sp < splits; ++sp) {
            const bhalf8 p0 = *(const bhalf8*)&po[(size_t)sp * ((size_t)B_ * H_ * N_ * HD_) + idx];
#pragma unroll
            for (int j = 0; j < 8; ++j) num[j] += (float)p0[j];
        }
        const float r = rden[m][hh];
        bhalf8 a0;
#pragma unroll
        for (int j = 0; j < 8; ++j) a0[j] = (bhalf)(num[j] * r);
        *(bhalf8*)&Alds[m][seg * 8] = a0;
    }

    const floatx4 zacc = {0.f, 0.f, 0.f, 0.f};
    floatx4 acc[2] = {zacc, zacc};

    // B staging: 512 threads, 256 rows x 32 k per chunk; thread covers 16 k.
    const int brow = tid >> 1, bkoff = (tid & 1) * 16;
    bhalf8 rb0 = *(const bhalf8*)&Wot[brow * C_ + bkoff];
    bhalf8 rb1 = *(const bhalf8*)&Wot[brow * C_ + bkoff + 8];
    *(bhalf8*)&Blds[0][brow][bkoff]     = rb0;
    *(bhalf8*)&Blds[0][brow][bkoff + 8] = rb1;

    int cur = 0;
    for (int kci = 0; kci < 8; ++kci) {
        __syncthreads();
        if (kci < 7) {
            const bhalf* wp = &Wot[brow * C_ + (kci + 1) * 32 + bkoff];
            rb0 = *(const bhalf8*)(wp);
            rb1 = *(const bhalf8*)(wp + 8);
        }
        const bhalf8 af = *(const bhalf8*)&Alds[l16][kci * 32 + quad * 8];
#pragma unroll
        for (int f = 0; f < 2; ++f) {
            const bhalf8 bfr = *(const bhalf8*)&Blds[cur][wave * 32 + f * 16 + l16][quad * 8];
            acc[f] = __builtin_amdgcn_mfma_f32_16x16x32_bf16(af, bfr, acc[f], 0, 0, 0);
        }
        if (kci < 7) {
            *(bhalf8*)&Blds[cur ^ 1][brow][bkoff]     = rb0;
            *(bhalf8*)&Blds[cur ^ 1][brow][bkoff + 8] = rb1;
        }
        cur ^= 1;
    }

    // epilogue: + bo + residual, LayerNorm over 256 cols (8 waves x 32 cols)
    float fv[2][4];
    float s1[4] = {0.f, 0.f, 0.f, 0.f}, s2[4] = {0.f, 0.f, 0.f, 0.f};
#pragma unroll
    for (int f = 0; f < 2; ++f) {
        const int col = wave * 32 + f * 16 + l16;
        const float bic = bo[col];
#pragma unroll
        for (int r = 0; r < 4; ++r) {
            const int m = quad * 4 + r;
            const float x = acc[f][r] + bic + feat[(row0 + m) * C_ + col];
            fv[f][r] = x;
            s1[r] += x; s2[r] += x * x;
        }
    }
#pragma unroll
    for (int r = 0; r < 4; ++r) {
        for (int o = 1; o < 16; o <<= 1) {
            s1[r] += __shfl_xor(s1[r], o);
            s2[r] += __shfl_xor(s2[r], o);
        }
    }
    if (l16 == 0) {
#pragma unroll
        for (int r = 0; r < 4; ++r) {
            wsum[wave][quad * 4 + r][0] = s1[r];
            wsum[wave][quad * 4 + r][1] = s2[r];
        }
    }
    __syncthreads();
    if (tid < 16) {
        float a = 0.f, bsq = 0.f;
#pragma unroll
        for (int w = 0; w < 8; ++w) { a += wsum[w][tid][0]; bsq += wsum[w][tid][1]; }
        const float mu = a * (1.f / C_);
        const float var = bsq * (1.f / C_) - mu * mu;
        stats[tid][0] = mu;
        stats[tid][1] = rsqrtf(var + 1e-5f);
    }
    __syncthreads();
#pragma unroll
    for (int f = 0; f < 2; ++f) {
        const int col = wave * 32 + f * 16 + l16;
        const float gc = g[col], bc = bb[col];
#pragma unroll
        for (int r = 0; r < 4; ++r) {
            const int m = quad * 4 + r;
            out[(row0 + m) * C_ + col] = (fv[f][r] - stats[m][0]) * stats[m][1] * gc + bc;
        }
    }
}

extern "C" void kernel_launch(void* const* d_in, const int* in_sizes, int n_in,
                              void* d_out, int out_size, void* d_ws, size_t ws_size,
                              hipStream_t stream) {
    const float* feat = (const float*)d_in[0];
    const float* pts  = (const float*)d_in[1];
    const float* Wq   = (const float*)d_in[2];
    const float* bq   = (const float*)d_in[3];
    const float* Wk   = (const float*)d_in[4];
    const float* bk   = (const float*)d_in[5];
    const float* Wv   = (const float*)d_in[6];
    const float* bv   = (const float*)d_in[7];
    const float* Wo   = (const float*)d_in[8];
    const float* bo   = (const float*)d_in[9];
    const float* lng  = (const float*)d_in[10];
    const float* lnb  = (const float*)d_in[11];

    // Workspace map (bytes): round-8/11 layout.
    // Wtb @ 0        : 512 KB ; fb @ 524288 : 2 MB
    // qs  @ 2621440  : 2 MB ; kg @ 4718592 : 2 MB ; vt @ 6815744 : 2 MB
    // qext@ 8912896  : 64 KB ; kext @ 8978432 : 64 KB
    // pl  @ 9043968  : splits x 128 KB fp32
    // po  @ 9568256  : splits x 2 MB bf16
    char* w = (char*)d_ws;
    bhalf* Wtb  = (bhalf*)(w);
    bhalf* fb   = (bhalf*)(w + 524288);
    bhalf* qs   = (bhalf*)(w + 2621440);
    bhalf* kg   = (bhalf*)(w + 4718592);
    bhalf* vtp  = (bhalf*)(w + 6815744);
    bhalf* qext = (bhalf*)(w + 8912896);
    bhalf* kext = (bhalf*)(w + 8978432);
    float* pl   = (float*)(w + 9043968);
    bhalf* po   = (bhalf*)(w + 9568256);

    const int spbits = (ws_size >= 17956864u) ? 2 : 1;
    const int splits = 1 << spbits;

    prep_all<<<80 + B_ * N_ * C_ / 1024, 256, 0, stream>>>(
        Wq, Wk, Wv, Wo, pts, feat, Wtb, qext, kext, fb);
    qkv_gemm<<<dim3(B_ * N_ / 32, 12), 256, 0, stream>>>(
        fb, Wtb, bq, bk, bv, qs, kg, vtp);
    attn_kernel<<<dim3(N_ / 128, H_, B_ << spbits), 256, 0, stream>>>(
        qs, kg, vtp, qext, kext, po, pl, spbits);
    outln_gemm<<<B_ * N_ / 16, 512, 0, stream>>>(
        po, pl, Wtb + 3 * (C_ * C_), bo, feat, lng, lnb, (float*)d_out, splits);
}

// Round 13
// 123.780 us; speedup vs baseline: 1.1412x; 1.1412x over previous
//
#include <hip/hip_runtime.h>
#include <hip/hip_bf16.h>

#define B_ 2
#define N_ 2048
#define C_ 256
#define H_ 8
#define HD_ 32

typedef __bf16 bhalf;
typedef bhalf bhalf8 __attribute__((ext_vector_type(8)));
typedef bhalf bhalf4 __attribute__((ext_vector_type(4)));
typedef float floatx4 __attribute__((ext_vector_type(4)));
typedef short short4v __attribute__((ext_vector_type(4)));

__device__ __forceinline__ floatx4 mfma16x16x16bf16(bhalf4 a, bhalf4 b, floatx4 c) {
#if __has_builtin(__builtin_amdgcn_mfma_f32_16x16x16_bf16)
    return __builtin_amdgcn_mfma_f32_16x16x16_bf16(a, b, c, 0, 0, 0);
#else
    return __builtin_amdgcn_mfma_f32_16x16x16bf16_1k(
        __builtin_bit_cast(short4v, a), __builtin_bit_cast(short4v, b), c, 0, 0, 0);
#endif
}

// ---------------------------------------------------------------------------
// prep_all: fused preprocessing.
//   blocks 0..63   : transpose+convert W (fp32 [k][n]) -> Wt (bf16 [n][k])
//   blocks 64..79  : point-extension vectors (dist bias rides the MFMA)
//   blocks 80..1103: feat fp32 -> bf16
// ---------------------------------------------------------------------------
__global__ __launch_bounds__(256) void prep_all(
    const float* __restrict__ Wq, const float* __restrict__ Wk,
    const float* __restrict__ Wv, const float* __restrict__ Wo,
    const float* __restrict__ pts, const float* __restrict__ feat,
    bhalf* __restrict__ Wtb, bhalf* __restrict__ qext,
    bhalf* __restrict__ kext, bhalf* __restrict__ fb)
{
    __shared__ float T[64][65];
    const int bx = blockIdx.x;
    const int t = threadIdx.x;
    if (bx < 64) {
        const int wsel = bx >> 4;
        const float* W = wsel == 0 ? Wq : (wsel == 1 ? Wk : (wsel == 2 ? Wv : Wo));
        bhalf* dst = Wtb + (size_t)wsel * (C_ * C_);
        const int tile = bx & 15;
        const int kt = (tile >> 2) * 64, nt = (tile & 3) * 64;
        const int c4 = (t & 15) * 4;
#pragma unroll
        for (int i = 0; i < 4; ++i) {
            const int r = (t >> 4) + i * 16;
            const float4 w = *(const float4*)&W[(kt + r) * C_ + nt + c4];
            T[r][c4 + 0] = w.x; T[r][c4 + 1] = w.y; T[r][c4 + 2] = w.z; T[r][c4 + 3] = w.w;
        }
        __syncthreads();
#pragma unroll
        for (int i = 0; i < 4; ++i) {
            const int n = (t >> 4) + i * 16;
            bhalf4 o;
            o[0] = (bhalf)T[c4 + 0][n]; o[1] = (bhalf)T[c4 + 1][n];
            o[2] = (bhalf)T[c4 + 2][n]; o[3] = (bhalf)T[c4 + 3][n];
            *(bhalf4*)&dst[(nt + n) * C_ + kt + c4] = o;
        }
    } else if (bx < 80) {
        const int i = (bx - 64) * 256 + t;  // < B*N
        const float x = pts[i * 3 + 0], y = pts[i * 3 + 1], z = pts[i * 3 + 2];
        const float nn = x * x + y * y + z * z;
        const bhalf hi = (bhalf)nn;
        const bhalf lo = (bhalf)(nn - (float)hi);
        bhalf8 qe, ke;
        qe[0] = (bhalf)(2.f * x); qe[1] = (bhalf)(2.f * y); qe[2] = (bhalf)(2.f * z);
        qe[3] = (bhalf)(-(float)hi); qe[4] = (bhalf)(-(float)lo);
        qe[5] = (bhalf)1.f; qe[6] = (bhalf)1.f; qe[7] = (bhalf)0.f;
        ke[0] = (bhalf)x; ke[1] = (bhalf)y; ke[2] = (bhalf)z;
        ke[3] = (bhalf)1.f; ke[4] = (bhalf)1.f;
        ke[5] = (bhalf)(-(float)hi); ke[6] = (bhalf)(-(float)lo); ke[7] = (bhalf)0.f;
        *(bhalf8*)&qext[(size_t)i * 8] = qe;
        *(bhalf8*)&kext[(size_t)i * 8] = ke;
    } else {
        const int idx = ((bx - 80) * 256 + t) * 4;  // < B*N*C
        const float4 f = *(const float4*)&feat[idx];
        bhalf4 o;
        o[0] = (bhalf)f.x; o[1] = (bhalf)f.y; o[2] = (bhalf)f.z; o[3] = (bhalf)f.w;
        *(bhalf4*)&fb[idx] = o;
    }
}

// ---------------------------------------------------------------------------
// qkv_gemm: bf16 MFMA GEMM, M-tile 32, double-buffered LDS (1 barrier/chunk).
// grid (M/32, 12): y/4 -> Wq/Wk/Wv, y%4 -> 64-col tile.
// ---------------------------------------------------------------------------
__global__ __launch_bounds__(256) void qkv_gemm(
    const bhalf* __restrict__ fb, const bhalf* __restrict__ Wtb,
    const float* __restrict__ bq, const float* __restrict__ bk,
    const float* __restrict__ bv,
    bhalf* __restrict__ qs, bhalf* __restrict__ kg, bhalf* __restrict__ vt)
{
    __shared__ __align__(16) bhalf Alds[2][32][72];
    __shared__ __align__(16) bhalf Blds[2][64][72];

    const int tid = threadIdx.x;
    const int wave = tid >> 6, lane = tid & 63;
    const int quad = lane >> 4, l16 = lane & 15;
    const int m0 = blockIdx.x * 32;
    const int which = blockIdx.y >> 2;
    const int n0 = (blockIdx.y & 3) * 64;
    const bhalf* Wt = Wtb + (size_t)which * (C_ * C_);
    const int mw = (wave & 1) * 16;
    const int cw = (wave >> 1) * 32;

    const floatx4 zacc = {0.f, 0.f, 0.f, 0.f};
    floatx4 acc[2] = {zacc, zacc};

    const int arow = tid >> 3, aoff = (tid & 7) * 8;
    const int brow = tid >> 2, boff = (tid & 3) * 16;

    bhalf8 ra  = *(const bhalf8*)&fb[(m0 + arow) * C_ + aoff];
    bhalf8 rb0 = *(const bhalf8*)&Wt[(n0 + brow) * C_ + boff];
    bhalf8 rb1 = *(const bhalf8*)&Wt[(n0 + brow) * C_ + boff + 8];
    *(bhalf8*)&Alds[0][arow][aoff] = ra;
    *(bhalf8*)&Blds[0][brow][boff] = rb0;
    *(bhalf8*)&Blds[0][brow][boff + 8] = rb1;

    int cur = 0;
    for (int kci = 0; kci < 4; ++kci) {
        __syncthreads();
        if (kci < 3) {
            const int kc = (kci + 1) * 64;
            ra  = *(const bhalf8*)&fb[(m0 + arow) * C_ + kc + aoff];
            rb0 = *(const bhalf8*)&Wt[(n0 + brow) * C_ + kc + boff];
            rb1 = *(const bhalf8*)&Wt[(n0 + brow) * C_ + kc + boff + 8];
        }
        const bhalf8 a0 = *(const bhalf8*)&Alds[cur][mw + l16][quad * 8];
        const bhalf8 a1 = *(const bhalf8*)&Alds[cur][mw + l16][32 + quad * 8];
#pragma unroll
        for (int f = 0; f < 2; ++f) {
            const bhalf8 b0 = *(const bhalf8*)&Blds[cur][cw + f * 16 + l16][quad * 8];
            const bhalf8 b1 = *(const bhalf8*)&Blds[cur][cw + f * 16 + l16][32 + quad * 8];
            acc[f] = __builtin_amdgcn_mfma_f32_16x16x32_bf16(a0, b0, acc[f], 0, 0, 0);
            acc[f] = __builtin_amdgcn_mfma_f32_16x16x32_bf16(a1, b1, acc[f], 0, 0, 0);
        }
        if (kci < 3) {
            *(bhalf8*)&Alds[cur ^ 1][arow][aoff] = ra;
            *(bhalf8*)&Blds[cur ^ 1][brow][boff] = rb0;
            *(bhalf8*)&Blds[cur ^ 1][brow][boff + 8] = rb1;
        }
        cur ^= 1;
    }

    const float scale = 0.17677669529663687f;  // 1/sqrt(32)
    const float* bias = which == 0 ? bq : (which == 1 ? bk : bv);
#pragma unroll
    for (int f = 0; f < 2; ++f) {
        const int cg = n0 + cw + f * 16 + l16;
        const float bi = bias[cg];
        const int hh = cg >> 5, dd = cg & 31;
        const int m = m0 + mw + quad * 4;     // 4 consecutive rows
        const int bb = m >> 11, nn = m & (N_ - 1);
        if (which == 2) {
            bhalf4 vw;
#pragma unroll
            for (int r = 0; r < 4; ++r) vw[r] = (bhalf)(acc[f][r] + bi);
            *(bhalf4*)&vt[(((size_t)(bb * H_ + hh) * (N_ / 64) + (nn >> 6)) * HD_ + dd) * 64 + (nn & 63)] = vw;
        } else {
#pragma unroll
            for (int r = 0; r < 4; ++r) {
                const float val = acc[f][r] + bi;
                if (which == 0)
                    qs[((size_t)(bb * H_ + hh) * N_ + nn + r) * HD_ + dd] = (bhalf)(val * scale);
                else
                    kg[((size_t)(bb * H_ + hh) * N_ + nn + r) * HD_ + dd] = (bhalf)val;
            }
        }
    }
}

// ---------------------------------------------------------------------------
// attn_kernel: round-11 proven config. S^T = K @ Q^T; P^T stays in registers
// (B-layout for the K=16 PV MFMA). 32 queries per wave (two Q-frags share
// each K/V fragment read). Double-buffered LDS, one barrier/tile. Fixed-max
// softmax (logits <= ~1), split-K (1<<spbits).
// ---------------------------------------------------------------------------
__global__ __launch_bounds__(256) void attn_kernel(
    const bhalf* __restrict__ qs, const bhalf* __restrict__ kg,
    const bhalf* __restrict__ vt, const bhalf* __restrict__ qext,
    const bhalf* __restrict__ kext,
    bhalf* __restrict__ po, float* __restrict__ pl, int spbits)
{
    __shared__ __align__(16) bhalf Ks[2][64][40];
    __shared__ __align__(16) bhalf Vts[2][32][72];
    __shared__ __align__(16) bhalf Kes[2][64][8];

    const int tid = threadIdx.x;
    const int wave = tid >> 6, lane = tid & 63;
    const int quad = lane >> 4, l16 = lane & 15;
    const int n0 = blockIdx.x * 128;
    const int h = blockIdx.y;
    const int sp = blockIdx.z & ((1 << spbits) - 1);
    const int b = blockIdx.z >> spbits;
    const int bh = b * H_ + h;

    const int qrow0 = n0 + wave * 32 + l16;
    const int qrow1 = qrow0 + 16;
    const bhalf8 bq0 = *(const bhalf8*)&qs[((size_t)bh * N_ + qrow0) * HD_ + quad * 8];
    const bhalf8 bq1 = *(const bhalf8*)&qs[((size_t)bh * N_ + qrow1) * HD_ + quad * 8];
    bhalf8 zv8;
#pragma unroll
    for (int j = 0; j < 8; ++j) zv8[j] = (bhalf)0.f;
    const bhalf8 bqe0 = (quad == 0)
        ? *(const bhalf8*)&qext[(size_t)(b * N_ + qrow0) * 8] : zv8;
    const bhalf8 bqe1 = (quad == 0)
        ? *(const bhalf8*)&qext[(size_t)(b * N_ + qrow1) * 8] : zv8;

    const floatx4 zacc = {0.f, 0.f, 0.f, 0.f};
    floatx4 o00 = zacc, o01 = zacc, o10 = zacc, o11 = zacc;
    float ls0 = 0.f, ls1 = 0.f;

    const int skey = tid >> 2, sseg = tid & 3;
    const int vd = tid >> 3, vks = tid & 7;
    const int ekey = tid >> 1, eoff = (tid & 1) * 4;
    const int iters = (N_ >> spbits) / 64;
    const int mbase = sp * (N_ >> spbits);

    bhalf8 rk = *(const bhalf8*)&kg[((size_t)bh * N_ + mbase + skey) * HD_ + sseg * 8];
    bhalf8 rv = *(const bhalf8*)&vt[(((size_t)bh * (N_ / 64) + (mbase >> 6)) * HD_ + vd) * 64 + vks * 8];
    bhalf4 re;
    if (tid < 128) re = *(const bhalf4*)&kext[(size_t)(b * N_ + mbase + ekey) * 8 + eoff];
    *(bhalf8*)&Ks[0][skey][sseg * 8] = rk;
    *(bhalf8*)&Vts[0][vd][vks * 8] = rv;
    if (tid < 128) *(bhalf4*)&Kes[0][ekey][eoff] = re;

    int cur = 0;
    for (int it = 0; it < iters; ++it) {
        __syncthreads();
        if (it + 1 < iters) {
            const int m1 = mbase + (it + 1) * 64;
            rk = *(const bhalf8*)&kg[((size_t)bh * N_ + m1 + skey) * HD_ + sseg * 8];
            rv = *(const bhalf8*)&vt[(((size_t)bh * (N_ / 64) + (m1 >> 6)) * HD_ + vd) * 64 + vks * 8];
            if (tid < 128) re = *(const bhalf4*)&kext[(size_t)(b * N_ + m1 + ekey) * 8 + eoff];
        }
#pragma unroll
        for (int mt = 0; mt < 4; ++mt) {
            const bhalf8 ak_ = *(const bhalf8*)&Ks[cur][mt * 16 + l16][quad * 8];
            const bhalf8 ake = (quad == 0)
                ? *(const bhalf8*)&Kes[cur][mt * 16 + l16][0] : zv8;
            floatx4 st0 = __builtin_amdgcn_mfma_f32_16x16x32_bf16(ak_, bq0, zacc, 0, 0, 0);
            st0 = __builtin_amdgcn_mfma_f32_16x16x32_bf16(ake, bqe0, st0, 0, 0, 0);
            floatx4 st1 = __builtin_amdgcn_mfma_f32_16x16x32_bf16(ak_, bq1, zacc, 0, 0, 0);
            st1 = __builtin_amdgcn_mfma_f32_16x16x32_bf16(ake, bqe1, st1, 0, 0, 0);
            bhalf4 pt0, pt1;
#pragma unroll
            for (int r = 0; r < 4; ++r) {
                const float p0 = __expf(st0[r]);
                const float p1 = __expf(st1[r]);
                ls0 += p0; ls1 += p1;
                pt0[r] = (bhalf)p0; pt1[r] = (bhalf)p1;
            }
            const bhalf4 av0 = *(const bhalf4*)&Vts[cur][l16][mt * 16 + quad * 4];
            const bhalf4 av1 = *(const bhalf4*)&Vts[cur][16 + l16][mt * 16 + quad * 4];
            o00 = mfma16x16x16bf16(av0, pt0, o00);
            o01 = mfma16x16x16bf16(av1, pt0, o01);
            o10 = mfma16x16x16bf16(av0, pt1, o10);
            o11 = mfma16x16x16bf16(av1, pt1, o11);
        }
        if (it + 1 < iters) {
            *(bhalf8*)&Ks[cur ^ 1][skey][sseg * 8] = rk;
            *(bhalf8*)&Vts[cur ^ 1][vd][vks * 8] = rv;
            if (tid < 128) *(bhalf4*)&Kes[cur ^ 1][ekey][eoff] = re;
        }
        cur ^= 1;
    }

    ls0 += __shfl_xor(ls0, 16); ls0 += __shfl_xor(ls0, 32);
    ls1 += __shfl_xor(ls1, 16); ls1 += __shfl_xor(ls1, 32);

    const size_t pobase = (size_t)sp * ((size_t)B_ * H_ * N_ * HD_) + (size_t)bh * N_ * HD_;
    bhalf4 w00, w01, w10, w11;
#pragma unroll
    for (int r = 0; r < 4; ++r) {
        w00[r] = (bhalf)o00[r]; w01[r] = (bhalf)o01[r];
        w10[r] = (bhalf)o10[r]; w11[r] = (bhalf)o11[r];
    }
    *(bhalf4*)&po[pobase + (size_t)qrow0 * HD_ + quad * 4] = w00;
    *(bhalf4*)&po[pobase + (size_t)qrow0 * HD_ + 16 + quad * 4] = w01;
    *(bhalf4*)&po[pobase + (size_t)qrow1 * HD_ + quad * 4] = w10;
    *(bhalf4*)&po[pobase + (size_t)qrow1 * HD_ + 16 + quad * 4] = w11;
    if (lane < 16)
        pl[(size_t)sp * (B_ * H_ * N_) + (size_t)bh * N_ + qrow0] = ls0;
    else if (lane < 32)
        pl[(size_t)sp * (B_ * H_ * N_) + (size_t)bh * N_ + qrow1] = ls1;
}

// ---------------------------------------------------------------------------
// outln_gemm: fused combine + out-proj MFMA GEMM + residual + LayerNorm.
// 512 threads = 8 waves per block; 16-row x 256-col tile, each wave owns 32
// cols. Double-buffered B-chunks.
// ---------------------------------------------------------------------------
__global__ __launch_bounds__(512) void outln_gemm(
    const bhalf* __restrict__ po, const float* __restrict__ pl,
    const bhalf* __restrict__ Wot, const float* __restrict__ bo,
    const float* __restrict__ feat, const float* __restrict__ g,
    const float* __restrict__ bb, float* __restrict__ out, int splits)
{
    __shared__ __align__(16) bhalf Alds[16][264];
    __shared__ __align__(16) bhalf Blds[2][256][40];
    __shared__ float rden[16][8];
    __shared__ float wsum[8][16][2];
    __shared__ float stats[16][2];

    const int tid = threadIdx.x;
    const int wave = tid >> 6, lane = tid & 63;
    const int quad = lane >> 4, l16 = lane & 15;
    const int row0 = blockIdx.x * 16;

    if (tid < 128) {
        const int m = tid >> 3, hh = tid & 7;
        const int grow = row0 + m;
        const int b = grow >> 11, n = grow & (N_ - 1);
        float den = 0.f;
        for (int sp = 0; sp < splits; ++sp)
            den += pl[(size_t)sp * (B_ * H_ * N_) + (size_t)(b * H_ + hh) * N_ + n];
        rden[m][hh] = 1.f / den;
    }
    __syncthreads();

    {   // A staging: 512 threads, 16 rows x 256 k; thread covers 8 k.
        const int m = tid >> 5, seg = tid & 31;
        const int hh = seg >> 2, d0 = (seg & 3) * 8;
        const int grow = row0 + m;
        const int b = grow >> 11, n = grow & (N_ - 1);
        const size_t idx = ((size_t)(b * H_ + hh) * N_ + n) * HD_ + d0;
        float num[8];
#pragma unroll
        for (int j = 0; j < 8; ++j) num[j] = 0.f;
        for (int sp = 0; sp < splits; ++sp) {
            const bhalf8 p0 = *(const bhalf8*)&po[(size_t)sp * ((size_t)B_ * H_ * N_ * HD_) + idx];
#pragma unroll
            for (int j = 0; j < 8; ++j) num[j] += (float)p0[j];
        }
        const float r = rden[m][hh];
        bhalf8 a0;
#pragma unroll
        for (int j = 0; j < 8; ++j) a0[j] = (bhalf)(num[j] * r);
        *(bhalf8*)&Alds[m][seg * 8] = a0;
    }

    const floatx4 zacc = {0.f, 0.f, 0.f, 0.f};
    floatx4 acc[2] = {zacc, zacc};

    // B staging: 512 threads, 256 rows x 32 k per chunk; thread covers 16 k.
    const int brow = tid >> 1, bkoff = (tid & 1) * 16;
    bhalf8 rb0 = *(const bhalf8*)&Wot[brow * C_ + bkoff];
    bhalf8 rb1 = *(const bhalf8*)&Wot[brow * C_ + bkoff + 8];
    *(bhalf8*)&Blds[0][brow][bkoff]     = rb0;
    *(bhalf8*)&Blds[0][brow][bkoff + 8] = rb1;

    int cur = 0;
    for (int kci = 0; kci < 8; ++kci) {
        __syncthreads();
        if (kci < 7) {
            const bhalf* wp = &Wot[brow * C_ + (kci + 1) * 32 + bkoff];
            rb0 = *(const bhalf8*)(wp);
            rb1 = *(const bhalf8*)(wp + 8);
        }
        const bhalf8 af = *(const bhalf8*)&Alds[l16][kci * 32 + quad * 8];
#pragma unroll
        for (int f = 0; f < 2; ++f) {
            const bhalf8 bfr = *(const bhalf8*)&Blds[cur][wave * 32 + f * 16 + l16][quad * 8];
            acc[f] = __builtin_amdgcn_mfma_f32_16x16x32_bf16(af, bfr, acc[f], 0, 0, 0);
        }
        if (kci < 7) {
            *(bhalf8*)&Blds[cur ^ 1][brow][bkoff]     = rb0;
            *(bhalf8*)&Blds[cur ^ 1][brow][bkoff + 8] = rb1;
        }
        cur ^= 1;
    }

    // epilogue: + bo + residual, LayerNorm over 256 cols (8 waves x 32 cols)
    float fv[2][4];
    float s1[4] = {0.f, 0.f, 0.f, 0.f}, s2[4] = {0.f, 0.f, 0.f, 0.f};
#pragma unroll
    for (int f = 0; f < 2; ++f) {
        const int col = wave * 32 + f * 16 + l16;
        const float bic = bo[col];
#pragma unroll
        for (int r = 0; r < 4; ++r) {
            const int m = quad * 4 + r;
            const float x = acc[f][r] + bic + feat[(row0 + m) * C_ + col];
            fv[f][r] = x;
            s1[r] += x; s2[r] += x * x;
        }
    }
#pragma unroll
    for (int r = 0; r < 4; ++r) {
        for (int o = 1; o < 16; o <<= 1) {
            s1[r] += __shfl_xor(s1[r], o);
            s2[r] += __shfl_xor(s2[r], o);
        }
    }
    if (l16 == 0) {
#pragma unroll
        for (int r = 0; r < 4; ++r) {
            wsum[wave][quad * 4 + r][0] = s1[r];
            wsum[wave][quad * 4 + r][1] = s2[r];
        }
    }
    __syncthreads();
    if (tid < 16) {
        float a = 0.f, bsq = 0.f;
#pragma unroll
        for (int w = 0; w < 8; ++w) { a += wsum[w][tid][0]; bsq += wsum[w][tid][1]; }
        const float mu = a * (1.f / C_);
        const float var = bsq * (1.f / C_) - mu * mu;
        stats[tid][0] = mu;
        stats[tid][1] = rsqrtf(var + 1e-5f);
    }
    __syncthreads();
#pragma unroll
    for (int f = 0; f < 2; ++f) {
        const int col = wave * 32 + f * 16 + l16;
        const float gc = g[col], bc = bb[col];
#pragma unroll
        for (int r = 0; r < 4; ++r) {
            const int m = quad * 4 + r;
            out[(row0 + m) * C_ + col] = (fv[f][r] - stats[m][0]) * stats[m][1] * gc + bc;
        }
    }
}

extern "C" void kernel_launch(void* const* d_in, const int* in_sizes, int n_in,
                              void* d_out, int out_size, void* d_ws, size_t ws_size,
                              hipStream_t stream) {
    const float* feat = (const float*)d_in[0];
    const float* pts  = (const float*)d_in[1];
    const float* Wq   = (const float*)d_in[2];
    const float* bq   = (const float*)d_in[3];
    const float* Wk   = (const float*)d_in[4];
    const float* bk   = (const float*)d_in[5];
    const float* Wv   = (const float*)d_in[6];
    const float* bv   = (const float*)d_in[7];
    const float* Wo   = (const float*)d_in[8];
    const float* bo   = (const float*)d_in[9];
    const float* lng  = (const float*)d_in[10];
    const float* lnb  = (const float*)d_in[11];

    // Workspace map (bytes):
    // Wtb @ 0        : 512 KB ; fb @ 524288 : 2 MB
    // qs  @ 2621440  : 2 MB ; kg @ 4718592 : 2 MB ; vt @ 6815744 : 2 MB
    // qext@ 8912896  : 64 KB ; kext @ 8978432 : 64 KB
    // pl  @ 9043968  : splits x 128 KB fp32 (max 8 -> 1 MB)
    // po  @ 10092544 : splits x 2 MB bf16   (max 8 -> 16 MB)
    char* w = (char*)d_ws;
    bhalf* Wtb  = (bhalf*)(w);
    bhalf* fb   = (bhalf*)(w + 524288);
    bhalf* qs   = (bhalf*)(w + 2621440);
    bhalf* kg   = (bhalf*)(w + 4718592);
    bhalf* vtp  = (bhalf*)(w + 6815744);
    bhalf* qext = (bhalf*)(w + 8912896);
    bhalf* kext = (bhalf*)(w + 8978432);
    float* pl   = (float*)(w + 9043968);
    bhalf* po   = (bhalf*)(w + 10092544);

    const int spbits = (ws_size >= 26869760u) ? 3 : ((ws_size >= 18481152u) ? 2 : 1);
    const int splits = 1 << spbits;

    prep_all<<<80 + B_ * N_ * C_ / 1024, 256, 0, stream>>>(
        Wq, Wk, Wv, Wo, pts, feat, Wtb, qext, kext, fb);
    qkv_gemm<<<dim3(B_ * N_ / 32, 12), 256, 0, stream>>>(
        fb, Wtb, bq, bk, bv, qs, kg, vtp);
    attn_kernel<<<dim3(N_ / 128, H_, B_ << spbits), 256, 0, stream>>>(
        qs, kg, vtp, qext, kext, po, pl, spbits);
    outln_gemm<<<B_ * N_ / 16, 512, 0, stream>>>(
        po, pl, Wtb + 3 * (C_ * C_), bo, feat, lng, lnb, (float*)d_out, splits);
}

// Round 14
// 118.792 us; speedup vs baseline: 1.1891x; 1.0420x over previous
//
#include <hip/hip_runtime.h>
#include <hip/hip_bf16.h>

#define B_ 2
#define N_ 2048
#define C_ 256
#define H_ 8
#define HD_ 32

typedef __bf16 bhalf;
typedef bhalf bhalf8 __attribute__((ext_vector_type(8)));
typedef bhalf bhalf4 __attribute__((ext_vector_type(4)));
typedef float floatx4 __attribute__((ext_vector_type(4)));
typedef short short4v __attribute__((ext_vector_type(4)));

__device__ __forceinline__ floatx4 mfma16x16x16bf16(bhalf4 a, bhalf4 b, floatx4 c) {
#if __has_builtin(__builtin_amdgcn_mfma_f32_16x16x16_bf16)
    return __builtin_amdgcn_mfma_f32_16x16x16_bf16(a, b, c, 0, 0, 0);
#else
    return __builtin_amdgcn_mfma_f32_16x16x16bf16_1k(
        __builtin_bit_cast(short4v, a), __builtin_bit_cast(short4v, b), c, 0, 0, 0);
#endif
}

__device__ __forceinline__ bhalf8 cvt8(const float* p) {
    const float4 a = *(const float4*)p;
    const float4 b = *(const float4*)(p + 4);
    bhalf8 o;
    o[0] = (bhalf)a.x; o[1] = (bhalf)a.y; o[2] = (bhalf)a.z; o[3] = (bhalf)a.w;
    o[4] = (bhalf)b.x; o[5] = (bhalf)b.y; o[6] = (bhalf)b.z; o[7] = (bhalf)b.w;
    return o;
}

// ---------------------------------------------------------------------------
// prep_all: blocks 0..63: transpose+convert W -> Wt (bf16 [n][k]);
//           blocks 64..79: point-extension vectors (dist bias rides the MFMA).
// ---------------------------------------------------------------------------
__global__ __launch_bounds__(256) void prep_all(
    const float* __restrict__ Wq, const float* __restrict__ Wk,
    const float* __restrict__ Wv, const float* __restrict__ Wo,
    const float* __restrict__ pts,
    bhalf* __restrict__ Wtb, bhalf* __restrict__ qext,
    bhalf* __restrict__ kext)
{
    __shared__ float T[64][65];
    const int bx = blockIdx.x;
    const int t = threadIdx.x;
    if (bx < 64) {
        const int wsel = bx >> 4;
        const float* W = wsel == 0 ? Wq : (wsel == 1 ? Wk : (wsel == 2 ? Wv : Wo));
        bhalf* dst = Wtb + (size_t)wsel * (C_ * C_);
        const int tile = bx & 15;
        const int kt = (tile >> 2) * 64, nt = (tile & 3) * 64;
        const int c4 = (t & 15) * 4;
#pragma unroll
        for (int i = 0; i < 4; ++i) {
            const int r = (t >> 4) + i * 16;
            const float4 w = *(const float4*)&W[(kt + r) * C_ + nt + c4];
            T[r][c4 + 0] = w.x; T[r][c4 + 1] = w.y; T[r][c4 + 2] = w.z; T[r][c4 + 3] = w.w;
        }
        __syncthreads();
#pragma unroll
        for (int i = 0; i < 4; ++i) {
            const int n = (t >> 4) + i * 16;
            bhalf4 o;
            o[0] = (bhalf)T[c4 + 0][n]; o[1] = (bhalf)T[c4 + 1][n];
            o[2] = (bhalf)T[c4 + 2][n]; o[3] = (bhalf)T[c4 + 3][n];
            *(bhalf4*)&dst[(nt + n) * C_ + kt + c4] = o;
        }
    } else {
        const int i = (bx - 64) * 256 + t;  // < B*N
        const float x = pts[i * 3 + 0], y = pts[i * 3 + 1], z = pts[i * 3 + 2];
        const float nn = x * x + y * y + z * z;
        const bhalf hi = (bhalf)nn;
        const bhalf lo = (bhalf)(nn - (float)hi);
        bhalf8 qe, ke;
        qe[0] = (bhalf)(2.f * x); qe[1] = (bhalf)(2.f * y); qe[2] = (bhalf)(2.f * z);
        qe[3] = (bhalf)(-(float)hi); qe[4] = (bhalf)(-(float)lo);
        qe[5] = (bhalf)1.f; qe[6] = (bhalf)1.f; qe[7] = (bhalf)0.f;
        ke[0] = (bhalf)x; ke[1] = (bhalf)y; ke[2] = (bhalf)z;
        ke[3] = (bhalf)1.f; ke[4] = (bhalf)1.f;
        ke[5] = (bhalf)(-(float)hi); ke[6] = (bhalf)(-(float)lo); ke[7] = (bhalf)0.f;
        *(bhalf8*)&qext[(size_t)i * 8] = qe;
        *(bhalf8*)&kext[(size_t)i * 8] = ke;
    }
}

// ---------------------------------------------------------------------------
// qkv_gemm: bf16 MFMA GEMM, M-tile 32, double-buffered LDS (1 barrier/chunk).
// A-staging converts fp32 feat -> bf16 inline (no fb intermediate).
// grid (M/32, 12): y/4 -> Wq/Wk/Wv, y%4 -> 64-col tile.
// ---------------------------------------------------------------------------
__global__ __launch_bounds__(256) void qkv_gemm(
    const float* __restrict__ feat, const bhalf* __restrict__ Wtb,
    const float* __restrict__ bq, const float* __restrict__ bk,
    const float* __restrict__ bv,
    bhalf* __restrict__ qs, bhalf* __restrict__ kg, bhalf* __restrict__ vt)
{
    __shared__ __align__(16) bhalf Alds[2][32][72];
    __shared__ __align__(16) bhalf Blds[2][64][72];

    const int tid = threadIdx.x;
    const int wave = tid >> 6, lane = tid & 63;
    const int quad = lane >> 4, l16 = lane & 15;
    const int m0 = blockIdx.x * 32;
    const int which = blockIdx.y >> 2;
    const int n0 = (blockIdx.y & 3) * 64;
    const bhalf* Wt = Wtb + (size_t)which * (C_ * C_);
    const int mw = (wave & 1) * 16;
    const int cw = (wave >> 1) * 32;

    const floatx4 zacc = {0.f, 0.f, 0.f, 0.f};
    floatx4 acc[2] = {zacc, zacc};

    const int arow = tid >> 3, aoff = (tid & 7) * 8;
    const int brow = tid >> 2, boff = (tid & 3) * 16;

    bhalf8 ra  = cvt8(&feat[(m0 + arow) * C_ + aoff]);
    bhalf8 rb0 = *(const bhalf8*)&Wt[(n0 + brow) * C_ + boff];
    bhalf8 rb1 = *(const bhalf8*)&Wt[(n0 + brow) * C_ + boff + 8];
    *(bhalf8*)&Alds[0][arow][aoff] = ra;
    *(bhalf8*)&Blds[0][brow][boff] = rb0;
    *(bhalf8*)&Blds[0][brow][boff + 8] = rb1;

    int cur = 0;
    for (int kci = 0; kci < 4; ++kci) {
        __syncthreads();
        if (kci < 3) {
            const int kc = (kci + 1) * 64;
            ra  = cvt8(&feat[(m0 + arow) * C_ + kc + aoff]);
            rb0 = *(const bhalf8*)&Wt[(n0 + brow) * C_ + kc + boff];
            rb1 = *(const bhalf8*)&Wt[(n0 + brow) * C_ + kc + boff + 8];
        }
        const bhalf8 a0 = *(const bhalf8*)&Alds[cur][mw + l16][quad * 8];
        const bhalf8 a1 = *(const bhalf8*)&Alds[cur][mw + l16][32 + quad * 8];
#pragma unroll
        for (int f = 0; f < 2; ++f) {
            const bhalf8 b0 = *(const bhalf8*)&Blds[cur][cw + f * 16 + l16][quad * 8];
            const bhalf8 b1 = *(const bhalf8*)&Blds[cur][cw + f * 16 + l16][32 + quad * 8];
            acc[f] = __builtin_amdgcn_mfma_f32_16x16x32_bf16(a0, b0, acc[f], 0, 0, 0);
            acc[f] = __builtin_amdgcn_mfma_f32_16x16x32_bf16(a1, b1, acc[f], 0, 0, 0);
        }
        if (kci < 3) {
            *(bhalf8*)&Alds[cur ^ 1][arow][aoff] = ra;
            *(bhalf8*)&Blds[cur ^ 1][brow][boff] = rb0;
            *(bhalf8*)&Blds[cur ^ 1][brow][boff + 8] = rb1;
        }
        cur ^= 1;
    }

    const float scale = 0.17677669529663687f;  // 1/sqrt(32)
    const float* bias = which == 0 ? bq : (which == 1 ? bk : bv);
#pragma unroll
    for (int f = 0; f < 2; ++f) {
        const int cg = n0 + cw + f * 16 + l16;
        const float bi = bias[cg];
        const int hh = cg >> 5, dd = cg & 31;
        const int m = m0 + mw + quad * 4;     // 4 consecutive rows
        const int bb = m >> 11, nn = m & (N_ - 1);
        if (which == 2) {
            bhalf4 vw;
#pragma unroll
            for (int r = 0; r < 4; ++r) vw[r] = (bhalf)(acc[f][r] + bi);
            *(bhalf4*)&vt[(((size_t)(bb * H_ + hh) * (N_ / 64) + (nn >> 6)) * HD_ + dd) * 64 + (nn & 63)] = vw;
        } else {
#pragma unroll
            for (int r = 0; r < 4; ++r) {
                const float val = acc[f][r] + bi;
                if (which == 0)
                    qs[((size_t)(bb * H_ + hh) * N_ + nn + r) * HD_ + dd] = (bhalf)(val * scale);
                else
                    kg[((size_t)(bb * H_ + hh) * N_ + nn + r) * HD_ + dd] = (bhalf)val;
            }
        }
    }
}

// ---------------------------------------------------------------------------
// attn_kernel: round-11 proven config. S^T = K @ Q^T; P^T stays in registers
// (B-layout for the K=16 PV MFMA). 32 queries per wave (two Q-frags share
// each K/V fragment read). Double-buffered LDS, one barrier/tile. Fixed-max
// softmax (logits <= ~1), split-K (1<<spbits).
// ---------------------------------------------------------------------------
__global__ __launch_bounds__(256) void attn_kernel(
    const bhalf* __restrict__ qs, const bhalf* __restrict__ kg,
    const bhalf* __restrict__ vt, const bhalf* __restrict__ qext,
    const bhalf* __restrict__ kext,
    bhalf* __restrict__ po, float* __restrict__ pl, int spbits)
{
    __shared__ __align__(16) bhalf Ks[2][64][40];
    __shared__ __align__(16) bhalf Vts[2][32][72];
    __shared__ __align__(16) bhalf Kes[2][64][8];

    const int tid = threadIdx.x;
    const int wave = tid >> 6, lane = tid & 63;
    const int quad = lane >> 4, l16 = lane & 15;
    const int n0 = blockIdx.x * 128;
    const int h = blockIdx.y;
    const int sp = blockIdx.z & ((1 << spbits) - 1);
    const int b = blockIdx.z >> spbits;
    const int bh = b * H_ + h;

    const int qrow0 = n0 + wave * 32 + l16;
    const int qrow1 = qrow0 + 16;
    const bhalf8 bq0 = *(const bhalf8*)&qs[((size_t)bh * N_ + qrow0) * HD_ + quad * 8];
    const bhalf8 bq1 = *(const bhalf8*)&qs[((size_t)bh * N_ + qrow1) * HD_ + quad * 8];
    bhalf8 zv8;
#pragma unroll
    for (int j = 0; j < 8; ++j) zv8[j] = (bhalf)0.f;
    const bhalf8 bqe0 = (quad == 0)
        ? *(const bhalf8*)&qext[(size_t)(b * N_ + qrow0) * 8] : zv8;
    const bhalf8 bqe1 = (quad == 0)
        ? *(const bhalf8*)&qext[(size_t)(b * N_ + qrow1) * 8] : zv8;

    const floatx4 zacc = {0.f, 0.f, 0.f, 0.f};
    floatx4 o00 = zacc, o01 = zacc, o10 = zacc, o11 = zacc;
    float ls0 = 0.f, ls1 = 0.f;

    const int skey = tid >> 2, sseg = tid & 3;
    const int vd = tid >> 3, vks = tid & 7;
    const int ekey = tid >> 1, eoff = (tid & 1) * 4;
    const int iters = (N_ >> spbits) / 64;
    const int mbase = sp * (N_ >> spbits);

    bhalf8 rk = *(const bhalf8*)&kg[((size_t)bh * N_ + mbase + skey) * HD_ + sseg * 8];
    bhalf8 rv = *(const bhalf8*)&vt[(((size_t)bh * (N_ / 64) + (mbase >> 6)) * HD_ + vd) * 64 + vks * 8];
    bhalf4 re;
    if (tid < 128) re = *(const bhalf4*)&kext[(size_t)(b * N_ + mbase + ekey) * 8 + eoff];
    *(bhalf8*)&Ks[0][skey][sseg * 8] = rk;
    *(bhalf8*)&Vts[0][vd][vks * 8] = rv;
    if (tid < 128) *(bhalf4*)&Kes[0][ekey][eoff] = re;

    int cur = 0;
    for (int it = 0; it < iters; ++it) {
        __syncthreads();
        if (it + 1 < iters) {
            const int m1 = mbase + (it + 1) * 64;
            rk = *(const bhalf8*)&kg[((size_t)bh * N_ + m1 + skey) * HD_ + sseg * 8];
            rv = *(const bhalf8*)&vt[(((size_t)bh * (N_ / 64) + (m1 >> 6)) * HD_ + vd) * 64 + vks * 8];
            if (tid < 128) re = *(const bhalf4*)&kext[(size_t)(b * N_ + m1 + ekey) * 8 + eoff];
        }
#pragma unroll
        for (int mt = 0; mt < 4; ++mt) {
            const bhalf8 ak_ = *(const bhalf8*)&Ks[cur][mt * 16 + l16][quad * 8];
            const bhalf8 ake = (quad == 0)
                ? *(const bhalf8*)&Kes[cur][mt * 16 + l16][0] : zv8;
            floatx4 st0 = __builtin_amdgcn_mfma_f32_16x16x32_bf16(ak_, bq0, zacc, 0, 0, 0);
            st0 = __builtin_amdgcn_mfma_f32_16x16x32_bf16(ake, bqe0, st0, 0, 0, 0);
            floatx4 st1 = __builtin_amdgcn_mfma_f32_16x16x32_bf16(ak_, bq1, zacc, 0, 0, 0);
            st1 = __builtin_amdgcn_mfma_f32_16x16x32_bf16(ake, bqe1, st1, 0, 0, 0);
            bhalf4 pt0, pt1;
#pragma unroll
            for (int r = 0; r < 4; ++r) {
                const float p0 = __expf(st0[r]);
                const float p1 = __expf(st1[r]);
                ls0 += p0; ls1 += p1;
                pt0[r] = (bhalf)p0; pt1[r] = (bhalf)p1;
            }
            const bhalf4 av0 = *(const bhalf4*)&Vts[cur][l16][mt * 16 + quad * 4];
            const bhalf4 av1 = *(const bhalf4*)&Vts[cur][16 + l16][mt * 16 + quad * 4];
            o00 = mfma16x16x16bf16(av0, pt0, o00);
            o01 = mfma16x16x16bf16(av1, pt0, o01);
            o10 = mfma16x16x16bf16(av0, pt1, o10);
            o11 = mfma16x16x16bf16(av1, pt1, o11);
        }
        if (it + 1 < iters) {
            *(bhalf8*)&Ks[cur ^ 1][skey][sseg * 8] = rk;
            *(bhalf8*)&Vts[cur ^ 1][vd][vks * 8] = rv;
            if (tid < 128) *(bhalf4*)&Kes[cur ^ 1][ekey][eoff] = re;
        }
        cur ^= 1;
    }

    ls0 += __shfl_xor(ls0, 16); ls0 += __shfl_xor(ls0, 32);
    ls1 += __shfl_xor(ls1, 16); ls1 += __shfl_xor(ls1, 32);

    const size_t pobase = (size_t)sp * ((size_t)B_ * H_ * N_ * HD_) + (size_t)bh * N_ * HD_;
    bhalf4 w00, w01, w10, w11;
#pragma unroll
    for (int r = 0; r < 4; ++r) {
        w00[r] = (bhalf)o00[r]; w01[r] = (bhalf)o01[r];
        w10[r] = (bhalf)o10[r]; w11[r] = (bhalf)o11[r];
    }
    *(bhalf4*)&po[pobase + (size_t)qrow0 * HD_ + quad * 4] = w00;
    *(bhalf4*)&po[pobase + (size_t)qrow0 * HD_ + 16 + quad * 4] = w01;
    *(bhalf4*)&po[pobase + (size_t)qrow1 * HD_ + quad * 4] = w10;
    *(bhalf4*)&po[pobase + (size_t)qrow1 * HD_ + 16 + quad * 4] = w11;
    if (lane < 16)
        pl[(size_t)sp * (B_ * H_ * N_) + (size_t)bh * N_ + qrow0] = ls0;
    else if (lane < 32)
        pl[(size_t)sp * (B_ * H_ * N_) + (size_t)bh * N_ + qrow1] = ls1;
}

// ---------------------------------------------------------------------------
// outln_gemm: fused combine + out-proj MFMA GEMM + residual + LayerNorm.
// 512 threads = 8 waves per block; 16-row x 256-col tile, each wave owns 32
// cols. Double-buffered B-chunks.
// ---------------------------------------------------------------------------
__global__ __launch_bounds__(512) void outln_gemm(
    const bhalf* __restrict__ po, const float* __restrict__ pl,
    const bhalf* __restrict__ Wot, const float* __restrict__ bo,
    const float* __restrict__ feat, const float* __restrict__ g,
    const float* __restrict__ bb, float* __restrict__ out, int splits)
{
    __shared__ __align__(16) bhalf Alds[16][264];
    __shared__ __align__(16) bhalf Blds[2][256][40];
    __shared__ float rden[16][8];
    __shared__ float wsum[8][16][2];
    __shared__ float stats[16][2];

    const int tid = threadIdx.x;
    const int wave = tid >> 6, lane = tid & 63;
    const int quad = lane >> 4, l16 = lane & 15;
    const int row0 = blockIdx.x * 16;

    if (tid < 128) {
        const int m = tid >> 3, hh = tid & 7;
        const int grow = row0 + m;
        const int b = grow >> 11, n = grow & (N_ - 1);
        float den = 0.f;
        for (int sp = 0; sp < splits; ++sp)
            den += pl[(size_t)sp * (B_ * H_ * N_) + (size_t)(b * H_ + hh) * N_ + n];
        rden[m][hh] = 1.f / den;
    }
    __syncthreads();

    {   // A staging: 512 threads, 16 rows x 256 k; thread covers 8 k.
        const int m = tid >> 5, seg = tid & 31;
        const int hh = seg >> 2, d0 = (seg & 3) * 8;
        const int grow = row0 + m;
        const int b = grow >> 11, n = grow & (N_ - 1);
        const size_t idx = ((size_t)(b * H_ + hh) * N_ + n) * HD_ + d0;
        float num[8];
#pragma unroll
        for (int j = 0; j < 8; ++j) num[j] = 0.f;
        for (int sp = 0; sp < splits; ++sp) {
            const bhalf8 p0 = *(const bhalf8*)&po[(size_t)sp * ((size_t)B_ * H_ * N_ * HD_) + idx];
#pragma unroll
            for (int j = 0; j < 8; ++j) num[j] += (float)p0[j];
        }
        const float r = rden[m][hh];
        bhalf8 a0;
#pragma unroll
        for (int j = 0; j < 8; ++j) a0[j] = (bhalf)(num[j] * r);
        *(bhalf8*)&Alds[m][seg * 8] = a0;
    }

    const floatx4 zacc = {0.f, 0.f, 0.f, 0.f};
    floatx4 acc[2] = {zacc, zacc};

    // B staging: 512 threads, 256 rows x 32 k per chunk; thread covers 16 k.
    const int brow = tid >> 1, bkoff = (tid & 1) * 16;
    bhalf8 rb0 = *(const bhalf8*)&Wot[brow * C_ + bkoff];
    bhalf8 rb1 = *(const bhalf8*)&Wot[brow * C_ + bkoff + 8];
    *(bhalf8*)&Blds[0][brow][bkoff]     = rb0;
    *(bhalf8*)&Blds[0][brow][bkoff + 8] = rb1;

    int cur = 0;
    for (int kci = 0; kci < 8; ++kci) {
        __syncthreads();
        if (kci < 7) {
            const bhalf* wp = &Wot[brow * C_ + (kci + 1) * 32 + bkoff];
            rb0 = *(const bhalf8*)(wp);
            rb1 = *(const bhalf8*)(wp + 8);
        }
        const bhalf8 af = *(const bhalf8*)&Alds[l16][kci * 32 + quad * 8];
#pragma unroll
        for (int f = 0; f < 2; ++f) {
            const bhalf8 bfr = *(const bhalf8*)&Blds[cur][wave * 32 + f * 16 + l16][quad * 8];
            acc[f] = __builtin_amdgcn_mfma_f32_16x16x32_bf16(af, bfr, acc[f], 0, 0, 0);
        }
        if (kci < 7) {
            *(bhalf8*)&Blds[cur ^ 1][brow][bkoff]     = rb0;
            *(bhalf8*)&Blds[cur ^ 1][brow][bkoff + 8] = rb1;
        }
        cur ^= 1;
    }

    // epilogue: + bo + residual, LayerNorm over 256 cols (8 waves x 32 cols)
    float fv[2][4];
    float s1[4] = {0.f, 0.f, 0.f, 0.f}, s2[4] = {0.f, 0.f, 0.f, 0.f};
#pragma unroll
    for (int f = 0; f < 2; ++f) {
        const int col = wave * 32 + f * 16 + l16;
        const float bic = bo[col];
#pragma unroll
        for (int r = 0; r < 4; ++r) {
            const int m = quad * 4 + r;
            const float x = acc[f][r] + bic + feat[(row0 + m) * C_ + col];
            fv[f][r] = x;
            s1[r] += x; s2[r] += x * x;
        }
    }
#pragma unroll
    for (int r = 0; r < 4; ++r) {
        for (int o = 1; o < 16; o <<= 1) {
            s1[r] += __shfl_xor(s1[r], o);
            s2[r] += __shfl_xor(s2[r], o);
        }
    }
    if (l16 == 0) {
#pragma unroll
        for (int r = 0; r < 4; ++r) {
            wsum[wave][quad * 4 + r][0] = s1[r];
            wsum[wave][quad * 4 + r][1] = s2[r];
        }
    }
    __syncthreads();
    if (tid < 16) {
        float a = 0.f, bsq = 0.f;
#pragma unroll
        for (int w = 0; w < 8; ++w) { a += wsum[w][tid][0]; bsq += wsum[w][tid][1]; }
        const float mu = a * (1.f / C_);
        const float var = bsq * (1.f / C_) - mu * mu;
        stats[tid][0] = mu;
        stats[tid][1] = rsqrtf(var + 1e-5f);
    }
    __syncthreads();
#pragma unroll
    for (int f = 0; f < 2; ++f) {
        const int col = wave * 32 + f * 16 + l16;
        const float gc = g[col], bc = bb[col];
#pragma unroll
        for (int r = 0; r < 4; ++r) {
            const int m = quad * 4 + r;
            out[(row0 + m) * C_ + col] = (fv[f][r] - stats[m][0]) * stats[m][1] * gc + bc;
        }
    }
}

extern "C" void kernel_launch(void* const* d_in, const int* in_sizes, int n_in,
                              void* d_out, int out_size, void* d_ws, size_t ws_size,
                              hipStream_t stream) {
    const float* feat = (const float*)d_in[0];
    const float* pts  = (const float*)d_in[1];
    const float* Wq   = (const float*)d_in[2];
    const float* bq   = (const float*)d_in[3];
    const float* Wk   = (const float*)d_in[4];
    const float* bk   = (const float*)d_in[5];
    const float* Wv   = (const float*)d_in[6];
    const float* bv   = (const float*)d_in[7];
    const float* Wo   = (const float*)d_in[8];
    const float* bo   = (const float*)d_in[9];
    const float* lng  = (const float*)d_in[10];
    const float* lnb  = (const float*)d_in[11];

    // Workspace map (bytes): round-11 layout (fb region retired, kept padding).
    // Wtb @ 0        : 512 KB
    // qs  @ 2621440  : 2 MB ; kg @ 4718592 : 2 MB ; vt @ 6815744 : 2 MB
    // qext@ 8912896  : 64 KB ; kext @ 8978432 : 64 KB
    // pl  @ 9043968  : splits x 128 KB fp32
    // po  @ 9568256  : splits x 2 MB bf16
    char* w = (char*)d_ws;
    bhalf* Wtb  = (bhalf*)(w);
    bhalf* qs   = (bhalf*)(w + 2621440);
    bhalf* kg   = (bhalf*)(w + 4718592);
    bhalf* vtp  = (bhalf*)(w + 6815744);
    bhalf* qext = (bhalf*)(w + 8912896);
    bhalf* kext = (bhalf*)(w + 8978432);
    float* pl   = (float*)(w + 9043968);
    bhalf* po   = (bhalf*)(w + 9568256);

    const int spbits = (ws_size >= 17956864u) ? 2 : 1;
    const int splits = 1 << spbits;

    prep_all<<<80, 256, 0, stream>>>(
        Wq, Wk, Wv, Wo, pts, Wtb, qext, kext);
    qkv_gemm<<<dim3(B_ * N_ / 32, 12), 256, 0, stream>>>(
        feat, Wtb, bq, bk, bv, qs, kg, vtp);
    attn_kernel<<<dim3(N_ / 128, H_, B_ << spbits), 256, 0, stream>>>(
        qs, kg, vtp, qext, kext, po, pl, spbits);
    outln_gemm<<<B_ * N_ / 16, 512, 0, stream>>>(
        po, pl, Wtb + 3 * (C_ * C_), bo, feat, lng, lnb, (float*)d_out, splits);
}